// Round 2
// baseline (1476.633 us; speedup 1.0000x reference)
//
#include <hip/hip_runtime.h>

typedef unsigned int u32;
typedef unsigned short ushort_t;

typedef __attribute__((ext_vector_type(4))) float f32x4;
typedef __attribute__((ext_vector_type(8))) __bf16 bf16x8;

// ---------- constants ----------
#define Cc 2
#define Ff 32
#define Hh 1024
#define Bb 16
#define Ss 2048
#define SF 2080   // S + F

// ---------- helpers ----------
__device__ __forceinline__ ushort_t f2bf(float f) {
  u32 u = __builtin_bit_cast(u32, f);
  u32 r = (u + 0x7fffu + ((u >> 16) & 1u)) >> 16;
  return (ushort_t)r;
}

typedef __attribute__((address_space(1))) const u32 u32_g;
typedef __attribute__((address_space(3))) u32 u32_l;

__device__ __forceinline__ void glds16(const void* g, void* l) {
  __builtin_amdgcn_global_load_lds((u32_g*)g, (u32_l*)l, 16, 0, 0);
}

__device__ __forceinline__ f32x4 mfma16(bf16x8 a, bf16x8 b, f32x4 c) {
  return __builtin_amdgcn_mfma_f32_16x16x32_bf16(a, b, c, 0, 0, 0);
}

// ---------- prep kernels ----------

// wvsum[c][h] = sum_o Wv[c][o][h]   (atomic partial sums; wvsum pre-zeroed)
__global__ void k_wvsum(const float* __restrict__ Wv, float* __restrict__ wvsum) {
  int idx = blockIdx.y * 256 + threadIdx.x;      // (c,h) pair, 2048 total
  int c = idx >> 10, h = idx & 1023;
  int o0 = blockIdx.x * 128;
  const float* p = Wv + (size_t)c * Hh * Hh + (size_t)o0 * Hh + h;
  float s = 0.f;
#pragma unroll 4
  for (int o = 0; o < 128; ++o) s += p[(size_t)o * Hh];
  atomicAdd(&wvsum[c * Hh + h], s);
}

// hidden f32 -> bf16, and vsum[c][row] = hidden_row . wvsum[c]
__global__ void k_hidden(const float* __restrict__ hidden, const float* __restrict__ wvsum,
                         ushort_t* __restrict__ hbf, float* __restrict__ vsum) {
  int row = blockIdx.x;            // 0..B*S-1
  int t = threadIdx.x;             // 256, each handles 4 floats
  const float4 hv = reinterpret_cast<const float4*>(hidden + (size_t)row * Hh)[t];
  ushort4 o4;
  o4.x = f2bf(hv.x); o4.y = f2bf(hv.y); o4.z = f2bf(hv.z); o4.w = f2bf(hv.w);
  reinterpret_cast<ushort4*>(hbf + (size_t)row * Hh)[t] = o4;
  float4 w0 = reinterpret_cast<const float4*>(wvsum)[t];
  float4 w1 = reinterpret_cast<const float4*>(wvsum + Hh)[t];
  float d0 = hv.x * w0.x + hv.y * w0.y + hv.z * w0.z + hv.w * w0.w;
  float d1 = hv.x * w1.x + hv.y * w1.y + hv.z * w1.z + hv.w * w1.w;
  for (int off = 32; off > 0; off >>= 1) {
    d0 += __shfl_down(d0, off);
    d1 += __shfl_down(d1, off);
  }
  __shared__ float red[2][4];
  int wave = t >> 6, lane = t & 63;
  if (lane == 0) { red[0][wave] = d0; red[1][wave] = d1; }
  __syncthreads();
  if (t == 0) {
    vsum[row]            = red[0][0] + red[0][1] + red[0][2] + red[0][3];
    vsum[Bb * Ss + row]  = red[1][0] + red[1][1] + red[1][2] + red[1][3];
  }
}

// transpose Wk,Wq: [c][o][h] f32 -> [c][h][o] bf16
__global__ void k_transpose(const float* __restrict__ Wk, const float* __restrict__ Wq,
                            ushort_t* __restrict__ WkT, ushort_t* __restrict__ WqT) {
  __shared__ float t[32][33];
  int zz = blockIdx.z; int mat = zz >> 1, c = zz & 1;
  const float* in = (mat ? Wq : Wk) + (size_t)c * Hh * Hh;
  ushort_t* out = (mat ? WqT : WkT) + (size_t)c * Hh * Hh;
  int h0 = blockIdx.x * 32, o0 = blockIdx.y * 32;
  int tx = threadIdx.x & 31, ty = threadIdx.x >> 5;
#pragma unroll
  for (int i = 0; i < 4; ++i)
    t[ty + 8 * i][tx] = in[(size_t)(o0 + ty + 8 * i) * Hh + h0 + tx];
  __syncthreads();
#pragma unroll
  for (int i = 0; i < 4; ++i)
    out[(size_t)(h0 + ty + 8 * i) * Hh + o0 + tx] = f2bf(t[tx][ty + 8 * i]);
}

// ef[c][f][h] = sum_o emb[c][f][o] * Wk[c][o][h]  (atomic partials; ef pre-zeroed)
__global__ void k_ef(const float* __restrict__ emb, const float* __restrict__ Wk,
                     float* __restrict__ ef) {
  int c = blockIdx.z;
  int h = blockIdx.y * 256 + threadIdx.x;
  int o0 = blockIdx.x * 128;
  __shared__ float es[Ff][129];
  for (int i = threadIdx.x; i < Ff * 128; i += 256) {
    int f = i >> 7, oo = i & 127;
    es[f][oo] = emb[(size_t)(c * Ff + f) * Hh + o0 + oo];
  }
  __syncthreads();
  float acc[Ff];
#pragma unroll
  for (int f = 0; f < Ff; ++f) acc[f] = 0.f;
  for (int oo = 0; oo < 128; ++oo) {
    float wk = Wk[(size_t)c * Hh * Hh + (size_t)(o0 + oo) * Hh + h];
#pragma unroll
    for (int f = 0; f < Ff; ++f) acc[f] += es[f][oo] * wk;
  }
#pragma unroll
  for (int f = 0; f < Ff; ++f)
    atomicAdd(&ef[(size_t)(c * Ff + f) * Hh + h], acc[f]);
}

// replicate ef rows (bf16) into Gaug tail rows for every b
__global__ void k_ef2g(const float* __restrict__ ef, ushort_t* __restrict__ Gaug) {
  int i = blockIdx.x * 256 + threadIdx.x;  // C*F*H = 65536
  int c = i >> 15, f = (i >> 10) & 31, h = i & 1023;
  ushort_t v = f2bf(ef[i]);
#pragma unroll
  for (int b = 0; b < Bb; ++b)
    Gaug[((size_t)(c * Bb + b) * SF + Ss + f) * Hh + h] = v;
}

// ---------- the shared NT GEMM (2-phase double-buffered) ----------
// C[m,n] = sum_k A[m,k]*B[n,k], K=1024, 128x128 tile, BK=64, 4 waves.
// MODE 0: MT = WkT @ WqT^T            (out bf16, M=N=1024, z=c)
// MODE 1: G  = hidden_bf @ MT^T       (out bf16 into Gaug w/ row remap, z=c)
// MODE 2: big scaled f32 out          (z = c*B+b, M=2080 bounds-checked)
template <int MODE>
__global__ __launch_bounds__(256, 2) void gemm_nt(
    const ushort_t* __restrict__ Aall, const ushort_t* __restrict__ Ball,
    void* __restrict__ Oall, const float* __restrict__ scaleAll) {
  constexpr int BK = 64;
  constexpr int NK = Hh / BK;   // 16
  constexpr int GX = (MODE == 0) ? 8 : (MODE == 1) ? 8 : 16;
  constexpr int GY = (MODE == 0) ? 8 : (MODE == 1) ? 256 : 17;
  constexpr int GZ = (MODE == 0) ? 2 : (MODE == 1) ? 2 : 32;
  constexpr int NWG = GX * GY * GZ;   // all divisible by 8

  const int tid = threadIdx.x;
  const int wave = tid >> 6, lane = tid & 63;
  const int wm = wave >> 1, wn = wave & 1;

  // bijective XCD-aware remap: XCD (fid&7) owns contiguous work chunk
  int fid = blockIdx.x + GX * (blockIdx.y + GY * blockIdx.z);
  int swz = (fid & 7) * (NWG >> 3) + (fid >> 3);
  const int bx = swz % GX;
  int tt = swz / GX;
  const int by = tt % GY;
  const int z  = tt / GY;

  const int row0 = by * 128;
  const int col0 = bx * 128;

  const ushort_t* A; const ushort_t* B;
  if constexpr (MODE == 0) {
    A = Aall + (size_t)z * Hh * Hh;
    B = Ball + (size_t)z * Hh * Hh;
  } else if constexpr (MODE == 1) {
    A = Aall;
    B = Ball + (size_t)z * Hh * Hh;
  } else {
    const int b = z & 15;
    A = Aall + (size_t)z * SF * Hh;
    B = Ball + (size_t)b * Ss * Hh;
  }

  __shared__ ushort_t As[2][128 * BK];
  __shared__ ushort_t Bs[2][128 * BK];
  constexpr int BUFB = 128 * BK * 2;  // bytes per buffer

  const ushort_t* gA[4]; const ushort_t* gB[4];
  char* lA[4]; char* lB[4];
#pragma unroll
  for (int r = 0; r < 4; ++r) {
    int chunk = r * 256 + wave * 64 + lane;     // 16B chunk id, 0..1023
    int rrow = chunk >> 3, kc = chunk & 7;
    gA[r] = A + (size_t)(row0 + rrow) * Hh + kc * 8;
    gB[r] = B + (size_t)(col0 + rrow) * Hh + kc * 8;
    lA[r] = (char*)&As[0][0] + (r * 256 + wave * 64) * 16;
    lB[r] = (char*)&Bs[0][0] + (r * 256 + wave * 64) * 16;
  }

  f32x4 acc[4][4];
#pragma unroll
  for (int i = 0; i < 4; ++i)
#pragma unroll
    for (int j = 0; j < 4; ++j) acc[i][j] = (f32x4){0.f, 0.f, 0.f, 0.f};

  const int lr = lane & 15, lk = lane >> 4;

  auto stage = [&](int buf) {
    const int boff = buf * BUFB;
#pragma unroll
    for (int r = 0; r < 4; ++r) glds16(gA[r], lA[r] + boff);
#pragma unroll
    for (int r = 0; r < 4; ++r) glds16(gB[r], lB[r] + boff);
#pragma unroll
    for (int r = 0; r < 4; ++r) { gA[r] += BK; gB[r] += BK; }
  };

  auto compute = [&](int buf) {
    const char* asb = (const char*)&As[buf][0];
    const char* bsb = (const char*)&Bs[buf][0];
#pragma unroll
    for (int ks = 0; ks < 2; ++ks) {
      bf16x8 af[4], bfr[4];
#pragma unroll
      for (int mt = 0; mt < 4; ++mt)
        af[mt] = *reinterpret_cast<const bf16x8*>(
            asb + (wm * 64 + mt * 16 + lr) * 128 + ks * 64 + lk * 16);
#pragma unroll
      for (int nt = 0; nt < 4; ++nt)
        bfr[nt] = *reinterpret_cast<const bf16x8*>(
            bsb + (wn * 64 + nt * 16 + lr) * 128 + ks * 64 + lk * 16);
#pragma unroll
      for (int mt = 0; mt < 4; ++mt)
#pragma unroll
        for (int nt = 0; nt < 4; ++nt)
          acc[mt][nt] = mfma16(af[mt], bfr[nt], acc[mt][nt]);
    }
  };

  // prologue: stage K-step 0 into buf 0
  stage(0);
  __syncthreads();              // vmcnt(0) + barrier
  for (int kit = 0; kit < NK - 1; ++kit) {
    const int cur = kit & 1;
    stage(cur ^ 1);             // prefetch K-step kit+1 (loads in flight over compute)
    compute(cur);
    __syncthreads();            // drains vmcnt(0): next buffer ready
  }
  compute((NK - 1) & 1);        // last K-step, no prefetch

  // epilogue: C/D layout col = lane&15, row = (lane>>4)*4 + reg
  if constexpr (MODE == 2) {
    const int c = z >> 4, b = z & 15;
    float* Out = (float*)Oall + (size_t)(b * Cc + c) * SF * Ss;
    const float* scale = scaleAll + (size_t)c * (Bb * Ss) + (size_t)b * Ss;
#pragma unroll
    for (int nt = 0; nt < 4; ++nt) {
      int col = col0 + wn * 64 + nt * 16 + lr;
      float s = scale[col];
#pragma unroll
      for (int mt = 0; mt < 4; ++mt) {
        int rbase = row0 + wm * 64 + mt * 16 + lk * 4;
#pragma unroll
        for (int r = 0; r < 4; ++r) {
          int orow = rbase + r;
          if (orow < SF) Out[(size_t)orow * Ss + col] = acc[mt][nt][r] * s;
        }
      }
    }
  } else {
    ushort_t* Out;
    if constexpr (MODE == 0) Out = (ushort_t*)Oall + (size_t)z * Hh * Hh;
    else Out = (ushort_t*)Oall + (size_t)z * (Bb * SF * Hh);
#pragma unroll
    for (int nt = 0; nt < 4; ++nt) {
      int col = col0 + wn * 64 + nt * 16 + lr;
#pragma unroll
      for (int mt = 0; mt < 4; ++mt) {
        int rbase = row0 + wm * 64 + mt * 16 + lk * 4;
#pragma unroll
        for (int r = 0; r < 4; ++r) {
          int m = rbase + r;
          size_t orow;
          if constexpr (MODE == 1) orow = (size_t)(m >> 11) * SF + (m & 2047);
          else orow = (size_t)m;
          Out[orow * Hh + col] = f2bf(acc[mt][nt][r]);
        }
      }
    }
  }
}

// ---------- launch ----------
extern "C" void kernel_launch(void* const* d_in, const int* in_sizes, int n_in,
                              void* d_out, int out_size, void* d_ws, size_t ws_size,
                              hipStream_t stream) {
  const float* hidden = (const float*)d_in[0];
  const float* emb    = (const float*)d_in[1];
  const float* Wk     = (const float*)d_in[2];
  const float* Wq     = (const float*)d_in[3];
  const float* Wv     = (const float*)d_in[4];
  float* out = (float*)d_out;

  char* base = (char*)d_ws;
  ushort_t* hbf   = (ushort_t*)(base);
  ushort_t* Gaug  = (ushort_t*)(base + 67108864);
  ushort_t* MTb   = (ushort_t*)(base + 203685888);
  ushort_t* WkT   = (ushort_t*)(base + 207880192);
  ushort_t* WqT   = (ushort_t*)(base + 212074496);
  float*    wvsum = (float*)  (base + 216268800);
  float*    efb   = (float*)  (base + 216276992);
  float*    vsum  = (float*)  (base + 216539136);

  hipMemsetAsync(wvsum, 0, 8192 + 262144, stream);  // wvsum + ef contiguous

  k_wvsum<<<dim3(8, 8), 256, 0, stream>>>(Wv, wvsum);
  k_hidden<<<Bb * Ss, 256, 0, stream>>>(hidden, wvsum, hbf, vsum);
  k_transpose<<<dim3(32, 32, 4), 256, 0, stream>>>(Wk, Wq, WkT, WqT);
  k_ef<<<dim3(8, 4, 2), 256, 0, stream>>>(emb, Wk, efb);

  gemm_nt<0><<<dim3(8, 8, 2), 256, 0, stream>>>(WkT, WqT, MTb, nullptr);
  gemm_nt<1><<<dim3(8, 256, 2), 256, 0, stream>>>(hbf, MTb, Gaug, nullptr);
  k_ef2g<<<256, 256, 0, stream>>>(efb, Gaug);
  gemm_nt<2><<<dim3(16, 17, 32), 256, 0, stream>>>(Gaug, hbf, out, vsum);
}

// Round 4
// 1208.655 us; speedup vs baseline: 1.2217x; 1.2217x over previous
//
#include <hip/hip_runtime.h>

typedef unsigned int u32;
typedef unsigned short ushort_t;

typedef __attribute__((ext_vector_type(4))) float f32x4;
typedef __attribute__((ext_vector_type(8))) __bf16 bf16x8;

// ---------- constants ----------
#define Cc 2
#define Ff 32
#define Hh 1024
#define Bb 16
#define Ss 2048
#define SF 2080   // S + F

// ---------- helpers ----------
__device__ __forceinline__ ushort_t f2bf(float f) {
  u32 u = __builtin_bit_cast(u32, f);
  u32 r = (u + 0x7fffu + ((u >> 16) & 1u)) >> 16;
  return (ushort_t)r;
}

typedef __attribute__((address_space(1))) const u32 u32_g;
typedef __attribute__((address_space(3))) u32 u32_l;

__device__ __forceinline__ void glds16(const void* g, void* l) {
  __builtin_amdgcn_global_load_lds((u32_g*)g, (u32_l*)l, 16, 0, 0);
}

__device__ __forceinline__ f32x4 mfma16(bf16x8 a, bf16x8 b, f32x4 c) {
  return __builtin_amdgcn_mfma_f32_16x16x32_bf16(a, b, c, 0, 0, 0);
}

// ---------- prep kernels (unchanged) ----------

__global__ void k_wvsum(const float* __restrict__ Wv, float* __restrict__ wvsum) {
  int idx = blockIdx.y * 256 + threadIdx.x;
  int c = idx >> 10, h = idx & 1023;
  int o0 = blockIdx.x * 128;
  const float* p = Wv + (size_t)c * Hh * Hh + (size_t)o0 * Hh + h;
  float s = 0.f;
#pragma unroll 4
  for (int o = 0; o < 128; ++o) s += p[(size_t)o * Hh];
  atomicAdd(&wvsum[c * Hh + h], s);
}

__global__ void k_hidden(const float* __restrict__ hidden, const float* __restrict__ wvsum,
                         ushort_t* __restrict__ hbf, float* __restrict__ vsum) {
  int row = blockIdx.x;
  int t = threadIdx.x;
  const float4 hv = reinterpret_cast<const float4*>(hidden + (size_t)row * Hh)[t];
  ushort4 o4;
  o4.x = f2bf(hv.x); o4.y = f2bf(hv.y); o4.z = f2bf(hv.z); o4.w = f2bf(hv.w);
  reinterpret_cast<ushort4*>(hbf + (size_t)row * Hh)[t] = o4;
  float4 w0 = reinterpret_cast<const float4*>(wvsum)[t];
  float4 w1 = reinterpret_cast<const float4*>(wvsum + Hh)[t];
  float d0 = hv.x * w0.x + hv.y * w0.y + hv.z * w0.z + hv.w * w0.w;
  float d1 = hv.x * w1.x + hv.y * w1.y + hv.z * w1.z + hv.w * w1.w;
  for (int off = 32; off > 0; off >>= 1) {
    d0 += __shfl_down(d0, off);
    d1 += __shfl_down(d1, off);
  }
  __shared__ float red[2][4];
  int wave = t >> 6, lane = t & 63;
  if (lane == 0) { red[0][wave] = d0; red[1][wave] = d1; }
  __syncthreads();
  if (t == 0) {
    vsum[row]            = red[0][0] + red[0][1] + red[0][2] + red[0][3];
    vsum[Bb * Ss + row]  = red[1][0] + red[1][1] + red[1][2] + red[1][3];
  }
}

__global__ void k_transpose(const float* __restrict__ Wk, const float* __restrict__ Wq,
                            ushort_t* __restrict__ WkT, ushort_t* __restrict__ WqT) {
  __shared__ float t[32][33];
  int zz = blockIdx.z; int mat = zz >> 1, c = zz & 1;
  const float* in = (mat ? Wq : Wk) + (size_t)c * Hh * Hh;
  ushort_t* out = (mat ? WqT : WkT) + (size_t)c * Hh * Hh;
  int h0 = blockIdx.x * 32, o0 = blockIdx.y * 32;
  int tx = threadIdx.x & 31, ty = threadIdx.x >> 5;
#pragma unroll
  for (int i = 0; i < 4; ++i)
    t[ty + 8 * i][tx] = in[(size_t)(o0 + ty + 8 * i) * Hh + h0 + tx];
  __syncthreads();
#pragma unroll
  for (int i = 0; i < 4; ++i)
    out[(size_t)(h0 + ty + 8 * i) * Hh + o0 + tx] = f2bf(t[tx][ty + 8 * i]);
}

__global__ void k_ef(const float* __restrict__ emb, const float* __restrict__ Wk,
                     float* __restrict__ ef) {
  int c = blockIdx.z;
  int h = blockIdx.y * 256 + threadIdx.x;
  int o0 = blockIdx.x * 128;
  __shared__ float es[Ff][129];
  for (int i = threadIdx.x; i < Ff * 128; i += 256) {
    int f = i >> 7, oo = i & 127;
    es[f][oo] = emb[(size_t)(c * Ff + f) * Hh + o0 + oo];
  }
  __syncthreads();
  float acc[Ff];
#pragma unroll
  for (int f = 0; f < Ff; ++f) acc[f] = 0.f;
  for (int oo = 0; oo < 128; ++oo) {
    float wk = Wk[(size_t)c * Hh * Hh + (size_t)(o0 + oo) * Hh + h];
#pragma unroll
    for (int f = 0; f < Ff; ++f) acc[f] += es[f][oo] * wk;
  }
#pragma unroll
  for (int f = 0; f < Ff; ++f)
    atomicAdd(&ef[(size_t)(c * Ff + f) * Hh + h], acc[f]);
}

__global__ void k_ef2g(const float* __restrict__ ef, ushort_t* __restrict__ Gaug) {
  int i = blockIdx.x * 256 + threadIdx.x;
  int c = i >> 15, f = (i >> 10) & 31, h = i & 1023;
  ushort_t v = f2bf(ef[i]);
#pragma unroll
  for (int b = 0; b < Bb; ++b)
    Gaug[((size_t)(c * Bb + b) * SF + Ss + f) * Hh + h] = v;
}

// ---------- 256x256 deep-pipelined NT GEMM ----------
// C[m,n] = sum_k A[m,k]*B[n,k], K=1024, BK=32, 512 thr (2x4 waves),
// ring-8 half-tile LDS (128 KiB), counted vmcnt(8), 1 barrier/K-tile,
// XOR-swizzled LDS via pre-swizzled global source, setprio around MFMA.
template <int MODE>
__global__ __launch_bounds__(512, 2) void gemm256(
    const ushort_t* __restrict__ Aall, const ushort_t* __restrict__ Ball,
    void* __restrict__ Oall, const float* __restrict__ scaleAll) {
  constexpr int BK = 32;
  constexpr int NK = Hh / BK;   // 32
  constexpr int GX = (MODE == 0) ? 4 : (MODE == 1) ? 4 : 8;
  constexpr int GY = (MODE == 0) ? 4 : (MODE == 1) ? 128 : 9;
  constexpr int GZ = (MODE == 0) ? 2 : (MODE == 1) ? 2 : 32;
  constexpr int NWG = GX * GY * GZ;   // all % 8 == 0

  const int tid = threadIdx.x;
  const int wave = tid >> 6, lane = tid & 63;
  const int wm = wave >> 2, wn = wave & 3;      // 2 x 4 wave grid
  const int lr = lane & 15, lk = lane >> 4;

  // bijective XCD-aware remap
  int fid = blockIdx.x + GX * (blockIdx.y + GY * blockIdx.z);
  int swz = (fid & 7) * (NWG >> 3) + (fid >> 3);
  const int bx = swz % GX;
  int tt2 = swz / GX;
  const int by = tt2 % GY;
  const int z  = tt2 / GY;

  const int row0 = by * 256;
  const int col0 = bx * 256;

  const ushort_t* A; const ushort_t* B;
  if constexpr (MODE == 0) {
    A = Aall + (size_t)z * Hh * Hh;
    B = Ball + (size_t)z * Hh * Hh;
  } else if constexpr (MODE == 1) {
    A = Aall;
    B = Ball + (size_t)z * Hh * Hh;
  } else {
    const int b = z & 15;
    A = Aall + (size_t)z * SF * Hh;
    B = Ball + (size_t)b * Ss * Hh;
  }

  // LDS: A ring 8 x 8KB, B ring 8 x 8KB
  __shared__ __align__(16) char lds[131072];
  char* ldsA = lds;
  char* ldsB = lds + 65536;

  // --- staging (global -> LDS, linear dest, inverse-swizzled source) ---
  // half-tile = 128 rows x 32k bf16 = 8KB; each wave stages 16 rows (1KB).
  const int srow = wave * 16 + (lane >> 2);                 // row in half
  const int kswz = ((lane & 3) ^ ((lane >> 3) & 3)) * 8;    // elements
  const ushort_t* gA0 = A + (size_t)(row0 + srow) * Hh + kswz;
  const ushort_t* gB0 = B + (size_t)(col0 + srow) * Hh + kswz;
  const int ldst = wave * 1024;

  auto stgA = [&](int t, int hf) {
    glds16(gA0 + (size_t)hf * 128 * Hh + t * BK,
           ldsA + (((2 * t + hf) & 7) << 13) + ldst);
  };
  auto stgB = [&](int t, int hf) {
    glds16(gB0 + (size_t)hf * 128 * Hh + t * BK,
           ldsB + (((2 * t + hf) & 7) << 13) + ldst);
  };

  f32x4 acc[8][4];
#pragma unroll
  for (int i = 0; i < 8; ++i)
#pragma unroll
    for (int j = 0; j < 4; ++j) acc[i][j] = (f32x4){0.f, 0.f, 0.f, 0.f};

  // per-thread swizzled ds_read base offsets
  const int sslot = lk ^ ((lr >> 1) & 3);
  const int aoff = lr * 64 + sslot * 16;
  const int boff = ((wn & 1) << 12) + aoff;

  // prologue: stage tiles 0,1,2 (12 loads/thread)
#pragma unroll
  for (int t = 0; t < 3; ++t) {
    stgA(t, 0); stgA(t, 1); stgB(t, 0); stgB(t, 1);
  }

  for (int t = 0; t < NK; ++t) {
    // tile-boundary: own loads for tile t done (tiles t+1,t+2 may fly), then barrier
    if (t < NK - 2)       asm volatile("s_waitcnt vmcnt(8)" ::: "memory");
    else if (t == NK - 2) asm volatile("s_waitcnt vmcnt(4)" ::: "memory");
    else                  asm volatile("s_waitcnt vmcnt(0)" ::: "memory");
    __builtin_amdgcn_s_barrier();
    __builtin_amdgcn_sched_barrier(0);

    const char* Apt = ldsA + (((2 * t + wm) & 7) << 13) + aoff;
    const char* Bpt = ldsB + (((2 * t + (wn >> 1)) & 7) << 13) + boff;

    // ---- phase 1: stage A(t+3), read B all + A low-half, 16 MFMA ----
    if (t < NK - 3) { stgA(t + 3, 0); stgA(t + 3, 1); }
    bf16x8 bfr[4];
#pragma unroll
    for (int nt = 0; nt < 4; ++nt)
      bfr[nt] = *reinterpret_cast<const bf16x8*>(Bpt + nt * 1024);
    bf16x8 afr[4];
#pragma unroll
    for (int mt = 0; mt < 4; ++mt)
      afr[mt] = *reinterpret_cast<const bf16x8*>(Apt + mt * 1024);
    asm volatile("s_waitcnt lgkmcnt(0)" ::: "memory");
    __builtin_amdgcn_sched_barrier(0);
    __builtin_amdgcn_s_setprio(1);
#pragma unroll
    for (int mt = 0; mt < 4; ++mt)
#pragma unroll
      for (int nt = 0; nt < 4; ++nt)
        acc[mt][nt] = mfma16(afr[mt], bfr[nt], acc[mt][nt]);
    __builtin_amdgcn_s_setprio(0);

    // ---- phase 2: stage B(t+3), read A high-half, 16 MFMA ----
    if (t < NK - 3) { stgB(t + 3, 0); stgB(t + 3, 1); }
    bf16x8 afr2[4];
#pragma unroll
    for (int mt = 0; mt < 4; ++mt)
      afr2[mt] = *reinterpret_cast<const bf16x8*>(Apt + (mt + 4) * 1024);
    asm volatile("s_waitcnt lgkmcnt(0)" ::: "memory");
    __builtin_amdgcn_sched_barrier(0);
    __builtin_amdgcn_s_setprio(1);
#pragma unroll
    for (int mt = 0; mt < 4; ++mt)
#pragma unroll
      for (int nt = 0; nt < 4; ++nt)
        acc[mt + 4][nt] = mfma16(afr2[mt], bfr[nt], acc[mt + 4][nt]);
    __builtin_amdgcn_s_setprio(0);
  }

  // ---- epilogue: C/D layout col = lane&15, row = (lane>>4)*4 + reg ----
  if constexpr (MODE == 2) {
    const int c = z >> 4, b = z & 15;
    float* Out = (float*)Oall + (size_t)(b * Cc + c) * SF * Ss;
    const float* scale = scaleAll + (size_t)c * (Bb * Ss) + (size_t)b * Ss;
#pragma unroll
    for (int nt = 0; nt < 4; ++nt) {
      int col = col0 + wn * 64 + nt * 16 + lr;
      float s = scale[col];
#pragma unroll
      for (int mt = 0; mt < 8; ++mt) {
        int rbase = row0 + wm * 128 + mt * 16 + lk * 4;
#pragma unroll
        for (int r = 0; r < 4; ++r) {
          int orow = rbase + r;
          if (orow < SF) Out[(size_t)orow * Ss + col] = acc[mt][nt][r] * s;
        }
      }
    }
  } else {
    ushort_t* Out;
    if constexpr (MODE == 0) Out = (ushort_t*)Oall + (size_t)z * Hh * Hh;
    else Out = (ushort_t*)Oall + (size_t)z * (Bb * SF * Hh);
#pragma unroll
    for (int nt = 0; nt < 4; ++nt) {
      int col = col0 + wn * 64 + nt * 16 + lr;
#pragma unroll
      for (int mt = 0; mt < 8; ++mt) {
        int rbase = row0 + wm * 128 + mt * 16 + lk * 4;
#pragma unroll
        for (int r = 0; r < 4; ++r) {
          int m = rbase + r;
          size_t orow;
          if constexpr (MODE == 1) orow = (size_t)(m >> 11) * SF + (m & 2047);
          else orow = (size_t)m;
          Out[orow * Hh + col] = f2bf(acc[mt][nt][r]);
        }
      }
    }
  }
}

// ---------- launch ----------
extern "C" void kernel_launch(void* const* d_in, const int* in_sizes, int n_in,
                              void* d_out, int out_size, void* d_ws, size_t ws_size,
                              hipStream_t stream) {
  const float* hidden = (const float*)d_in[0];
  const float* emb    = (const float*)d_in[1];
  const float* Wk     = (const float*)d_in[2];
  const float* Wq     = (const float*)d_in[3];
  const float* Wv     = (const float*)d_in[4];
  float* out = (float*)d_out;

  char* base = (char*)d_ws;
  ushort_t* hbf   = (ushort_t*)(base);
  ushort_t* Gaug  = (ushort_t*)(base + 67108864);
  ushort_t* MTb   = (ushort_t*)(base + 203685888);
  ushort_t* WkT   = (ushort_t*)(base + 207880192);
  ushort_t* WqT   = (ushort_t*)(base + 212074496);
  float*    wvsum = (float*)  (base + 216268800);
  float*    efb   = (float*)  (base + 216276992);
  float*    vsum  = (float*)  (base + 216539136);

  (void)hipMemsetAsync(wvsum, 0, 8192 + 262144, stream);  // wvsum + ef contiguous

  k_wvsum<<<dim3(8, 8), 256, 0, stream>>>(Wv, wvsum);
  k_hidden<<<Bb * Ss, 256, 0, stream>>>(hidden, wvsum, hbf, vsum);
  k_transpose<<<dim3(32, 32, 4), 256, 0, stream>>>(Wk, Wq, WkT, WqT);
  k_ef<<<dim3(8, 4, 2), 256, 0, stream>>>(emb, Wk, efb);

  gemm256<0><<<dim3(4, 4, 2), 512, 0, stream>>>(WkT, WqT, MTb, nullptr);
  gemm256<1><<<dim3(4, 128, 2), 512, 0, stream>>>(hbf, MTb, Gaug, nullptr);
  k_ef2g<<<256, 256, 0, stream>>>(efb, Gaug);
  gemm256<2><<<dim3(8, 9, 32), 512, 0, stream>>>(Gaug, hbf, out, vsum);
}